// Round 15
// baseline (264.938 us; speedup 1.0000x reference)
//
#include <hip/hip_runtime.h>

// ==== DIAGNOSTIC: grid-replicated k_mega x8 (R14 structure, id-offset cold
// gathers, store gated to rep 0).  Gets MfmaUtil/VALUBusy/FETCH/LDS-conflict
// counters for the current best kernel past the harness's ~150us fills.

#define B_SZ  16384
#define F_SZ  20
#define V_SZ  100000
#define E_SZ  32
#define DBOT  640
#define D1    512
#define D2    256
#define T1D   128
#define T2D   64
#define NDOM  4
#define REP_MEGA 8

typedef __bf16 bf16x8 __attribute__((ext_vector_type(8)));
typedef float  f32x4  __attribute__((ext_vector_type(4)));

#define MFMA(a, b, c) __builtin_amdgcn_mfma_f32_16x16x32_bf16((a), (b), (c), 0, 0, 0)

// ---------------------------------------------------------------------------
__global__ __launch_bounds__(256) void k_prep(const float* __restrict__ W1,
                                              const float* __restrict__ W2,
                                              const float* __restrict__ TW1,
                                              const float* __restrict__ TW2,
                                              __bf16* __restrict__ W1P,
                                              __bf16* __restrict__ W2P,
                                              __bf16* __restrict__ TW1P,
                                              __bf16* __restrict__ TW2P) {
  int bid = blockIdx.x, tid = threadIdx.x;
  const float* src; __bf16* dst; int n, k, N;
  if (bid < 160) {
    long g = (long)bid * 256 + tid;
    int lane = g & 63; int kkg = (int)((g >> 6) % 20); int ntile = (int)(g / 1280);
    n = ntile * 16 + (lane & 15); k = kkg * 32 + ((lane >> 4) << 3);
    src = W1; N = D1; dst = W1P + g * 8;
  } else if (bid < 224) {
    long g = (long)(bid - 160) * 256 + tid;
    int lane = g & 63; int kkg = (int)((g >> 6) & 15); int ntile = (int)(g >> 10);
    n = ntile * 16 + (lane & 15); k = kkg * 32 + ((lane >> 4) << 3);
    src = W2; N = D2; dst = W2P + g * 8;
  } else if (bid < 288) {
    long g = (long)(bid - 224) * 256 + tid;
    int d = (int)(g >> 12); long r = g & 4095;
    int lane = r & 63; int kkg = (int)((r >> 6) & 7); int ntile = (int)(r >> 9);
    n = ntile * 16 + (lane & 15); k = kkg * 32 + ((lane >> 4) << 3);
    src = TW1 + (long)d * D2 * T1D; N = T1D;
    dst = TW1P + ((long)(d * 64 + ntile * 8 + kkg) * 64 + lane) * 8;
  } else {
    long g = (long)(bid - 288) * 256 + tid;
    int d = (int)(g >> 10); long r = g & 1023;
    int lane = r & 63; int kkg = (int)((r >> 6) & 3); int ntile = (int)(r >> 8);
    n = ntile * 16 + (lane & 15); k = kkg * 32 + ((lane >> 4) << 3);
    src = TW2 + (long)d * T1D * T2D; N = T2D;
    dst = TW2P + ((long)(d * 16 + ntile * 4 + kkg) * 64 + lane) * 8;
  }
  bf16x8 o;
#pragma unroll
  for (int e = 0; e < 8; ++e) o[e] = (__bf16)src[(long)(k + e) * N + n];
  *(bf16x8*)dst = o;
}

// ---------------------------------------------------------------------------
__global__ __launch_bounds__(512) void k_mega(const int* __restrict__ fids,
                                              const int* __restrict__ dom,
                                              const float* __restrict__ emb,
                                              const __bf16* __restrict__ W1P,
                                              const float* __restrict__ b1,
                                              const __bf16* __restrict__ W2P,
                                              const float* __restrict__ b2,
                                              const __bf16* __restrict__ TW1P,
                                              const __bf16* __restrict__ TW2P,
                                              const float* __restrict__ Tb1,
                                              const float* __restrict__ Tb2,
                                              const float* __restrict__ TW3,
                                              const float* __restrict__ Tb3,
                                              float* __restrict__ out) {
  __shared__ __attribute__((aligned(16))) char smem[152576];
  int*    ids_lds = (int*)(smem + 147456);
  __bf16* sA      = (__bf16*)smem;
  __bf16* h1      = (__bf16*)(smem + 81920);
  __bf16* h2_lds  = (__bf16*)smem;
  __bf16* t_lds   = (__bf16*)(smem + 81920);

  int rep = blockIdx.x >> 8;          // 0..7; rep>0 = cold-gather replicas
  int bid = blockIdx.x & 255;
  int repoff = rep * 4999;
  int tid = threadIdx.x;
  int lane = tid & 63, w = tid >> 6;
  int lrow = lane & 15, kq = lane >> 4;
  int m0 = bid * 64;

  for (int i = tid; i < 64 * F_SZ; i += 512) ids_lds[i] = fids[m0 * F_SZ + i];
  __syncthreads();

#define GID(ROW, F) ({ int _i = ids_lds[(ROW) * F_SZ + (F)] + repoff;        \
                       if (_i >= V_SZ) _i -= V_SZ; _i; })

  int row0 = tid >> 4,          cc0 = tid & 15;
  int row1 = (tid + 512) >> 4,  cc1 = tid & 15;
  int sb0 = (row0 * 1280 + cc0 * 16) ^ ((row0 & 7) << 4);
  int sb1 = (row1 * 1280 + cc1 * 16) ^ ((row1 & 7) << 4);
  int f0base = cc0 >> 2, es0 = (cc0 & 3) << 3;
  int f1base = cc1 >> 2, es1 = (cc1 & 3) << 3;

  float4 g0a, g0b, g1a, g1b;
  {
    int f = f0base;
    int id = GID(row0, f);
    const float* p = emb + ((long)f * V_SZ + id) * E_SZ + es0;
    g0a = *(const float4*)p; g0b = *(const float4*)(p + 4);
    f = f1base;
    id = GID(row1, f);
    const float* q = emb + ((long)f * V_SZ + id) * E_SZ + es1;
    g1a = *(const float4*)q; g1b = *(const float4*)(q + 4);
  }

  f32x4 acc[4][4] = {};

#pragma unroll
  for (int g = 0; g < 5; ++g) {
    {
      bf16x8 o;
      o[0] = (__bf16)g0a.x; o[1] = (__bf16)g0a.y; o[2] = (__bf16)g0a.z; o[3] = (__bf16)g0a.w;
      o[4] = (__bf16)g0b.x; o[5] = (__bf16)g0b.y; o[6] = (__bf16)g0b.z; o[7] = (__bf16)g0b.w;
      *(bf16x8*)((char*)sA + sb0 + g * 256) = o;
      o[0] = (__bf16)g1a.x; o[1] = (__bf16)g1a.y; o[2] = (__bf16)g1a.z; o[3] = (__bf16)g1a.w;
      o[4] = (__bf16)g1b.x; o[5] = (__bf16)g1b.y; o[6] = (__bf16)g1b.z; o[7] = (__bf16)g1b.w;
      *(bf16x8*)((char*)sA + sb1 + g * 256) = o;
    }
    asm volatile("s_waitcnt lgkmcnt(0)" ::: "memory");
    __builtin_amdgcn_s_barrier();
    __builtin_amdgcn_sched_barrier(0);

    bf16x8 bfr[4][4];
#pragma unroll
    for (int f4 = 0; f4 < 4; ++f4)
#pragma unroll
      for (int ni = 0; ni < 4; ++ni)
        bfr[f4][ni] = *(const bf16x8*)(W1P +
            ((long)((w * 4 + ni) * 20 + g * 4 + f4) * 64 + lane) * 8);
    __builtin_amdgcn_sched_barrier(0);

    if (g < 4) {
      int f = (g + 1) * 4 + f0base;
      int id = GID(row0, f);
      const float* p = emb + ((long)f * V_SZ + id) * E_SZ + es0;
      g0a = *(const float4*)p; g0b = *(const float4*)(p + 4);
      f = (g + 1) * 4 + f1base;
      id = GID(row1, f);
      const float* q = emb + ((long)f * V_SZ + id) * E_SZ + es1;
      g1a = *(const float4*)q; g1b = *(const float4*)(q + 4);
    }
    __builtin_amdgcn_sched_barrier(0);

#pragma unroll
    for (int f4 = 0; f4 < 4; ++f4) {
      int f = g * 4 + f4;
      bf16x8 af[4];
#pragma unroll
      for (int mi = 0; mi < 4; ++mi) {
        int byte = ((mi * 16 + lrow) * 1280 + (f * 32 + kq * 8) * 2) ^ ((lrow & 7) << 4);
        af[mi] = *(const bf16x8*)((const char*)sA + byte);
      }
#pragma unroll
      for (int ni = 0; ni < 4; ++ni)
#pragma unroll
        for (int mi = 0; mi < 4; ++mi)
          acc[mi][ni] = MFMA(af[mi], bfr[f4][ni], acc[mi][ni]);
    }
  }
#undef GID

#pragma unroll
  for (int ni = 0; ni < 4; ++ni) {
    int col = w * 64 + ni * 16 + lrow;
    float bv = b1[col];
#pragma unroll
    for (int mi = 0; mi < 4; ++mi) {
#pragma unroll
      for (int r = 0; r < 4; ++r) {
        int row = mi * 16 + kq * 4 + r;
        float v = acc[mi][ni][r] + bv;
        v = v > 0.f ? v : 0.f;
        int byte = (row * 1024 + col * 2) ^ ((row & 7) << 4);
        *(__bf16*)((char*)h1 + byte) = (__bf16)v;
      }
    }
  }
  __syncthreads();

  {
    f32x4 acc2[4][2] = {};
#pragma unroll 4
    for (int kkg = 0; kkg < 16; ++kkg) {
      bf16x8 a2[4];
#pragma unroll
      for (int mi = 0; mi < 4; ++mi) {
        int byte = ((mi * 16 + lrow) * 1024 + kkg * 64 + kq * 16) ^ ((lrow & 7) << 4);
        a2[mi] = *(const bf16x8*)((const char*)h1 + byte);
      }
#pragma unroll
      for (int ni = 0; ni < 2; ++ni) {
        bf16x8 bfr2 = *(const bf16x8*)(W2P +
            ((long)((w * 2 + ni) * 16 + kkg) * 64 + lane) * 8);
#pragma unroll
        for (int mi = 0; mi < 4; ++mi)
          acc2[mi][ni] = MFMA(a2[mi], bfr2, acc2[mi][ni]);
      }
    }
#pragma unroll
    for (int ni = 0; ni < 2; ++ni) {
      int col = w * 32 + ni * 16 + lrow;
      float bv = b2[col];
#pragma unroll
      for (int mi = 0; mi < 4; ++mi) {
#pragma unroll
        for (int r = 0; r < 4; ++r) {
          int row = mi * 16 + kq * 4 + r;
          float v = acc2[mi][ni][r] + bv;
          v = v > 0.f ? v : 0.f;
          int byte = (row * 512 + col * 2) ^ ((row & 7) << 4);
          *(__bf16*)((char*)h2_lds + byte) = (__bf16)v;
        }
      }
    }
  }
  __syncthreads();

  {
    int d  = w >> 1;
    int r0 = (w & 1) * 32;
    __bf16* tw = t_lds + w * 4096;

    bf16x8 a1[2][8];
#pragma unroll
    for (int mi = 0; mi < 2; ++mi)
#pragma unroll
      for (int kk = 0; kk < 8; ++kk) {
        int row = r0 + mi * 16 + lrow;
        int byte = (row * 512 + (kk * 32 + kq * 8) * 2) ^ ((row & 7) << 4);
        a1[mi][kk] = *(const bf16x8*)((const char*)h2_lds + byte);
      }

    f32x4 acc1[2][8] = {};
#pragma unroll
    for (int kk = 0; kk < 8; ++kk) {
#pragma unroll
      for (int ni = 0; ni < 8; ++ni) {
        bf16x8 b = *(const bf16x8*)(TW1P +
            ((long)(d * 64 + ni * 8 + kk) * 64 + lane) * 8);
#pragma unroll
        for (int mi = 0; mi < 2; ++mi)
          acc1[mi][ni] = MFMA(a1[mi][kk], b, acc1[mi][ni]);
      }
    }
#pragma unroll
    for (int ni = 0; ni < 8; ++ni) {
      float bv = Tb1[d * T1D + ni * 16 + lrow];
#pragma unroll
      for (int mi = 0; mi < 2; ++mi) {
#pragma unroll
        for (int r = 0; r < 4; ++r) {
          int lr = mi * 16 + kq * 4 + r;
          float v = acc1[mi][ni][r] + bv;
          v = v > 0.f ? v : 0.f;
          int byte = (lr * 256 + (ni * 16 + lrow) * 2) ^ ((lr & 7) << 4);
          *(__bf16*)((char*)tw + byte) = (__bf16)v;
        }
      }
    }
    asm volatile("s_waitcnt lgkmcnt(0)" ::: "memory");

    bf16x8 a2f[2][4];
#pragma unroll
    for (int mi = 0; mi < 2; ++mi)
#pragma unroll
      for (int kk = 0; kk < 4; ++kk) {
        int lr = mi * 16 + lrow;
        int byte = (lr * 256 + (kk * 32 + kq * 8) * 2) ^ ((lr & 7) << 4);
        a2f[mi][kk] = *(const bf16x8*)((const char*)tw + byte);
      }
    asm volatile("s_waitcnt lgkmcnt(0)" ::: "memory");
    f32x4 acc2[2][4] = {};
#pragma unroll
    for (int kk = 0; kk < 4; ++kk) {
#pragma unroll
      for (int ni = 0; ni < 4; ++ni) {
        bf16x8 b = *(const bf16x8*)(TW2P +
            ((long)(d * 16 + ni * 4 + kk) * 64 + lane) * 8);
#pragma unroll
        for (int mi = 0; mi < 2; ++mi)
          acc2[mi][ni] = MFMA(a2f[mi][kk], b, acc2[mi][ni]);
      }
    }
#pragma unroll
    for (int ni = 0; ni < 4; ++ni) {
      float bv = Tb2[d * T2D + ni * 16 + lrow];
#pragma unroll
      for (int mi = 0; mi < 2; ++mi) {
#pragma unroll
        for (int r = 0; r < 4; ++r) {
          int lr = mi * 16 + kq * 4 + r;
          float v = acc2[mi][ni][r] + bv;
          v = v > 0.f ? v : 0.f;
          int byte = (lr * 128 + (ni * 16 + lrow) * 2) ^ ((lr & 7) << 4);
          *(__bf16*)((char*)tw + byte) = (__bf16)v;
        }
      }
    }
    asm volatile("s_waitcnt lgkmcnt(0)" ::: "memory");

    {
      int lr    = (kq & 1) * 16 + lrow;
      int khalf = kq >> 1;
      float s = 0.f;
#pragma unroll
      for (int j = 0; j < 32; ++j) {
        int col = khalf * 32 + j;
        int byte = (lr * 128 + col * 2) ^ ((lr & 7) << 4);
        s += (float)*(const __bf16*)((const char*)tw + byte) * TW3[d * T2D + col];
      }
      s += __shfl_xor(s, 32);
      s += Tb3[d];
      int grow = r0 + lr;
      if (khalf == 0 && rep == 0 && dom[m0 + grow] == d)
        out[m0 + grow] = 1.0f / (1.0f + expf(-s));
      else
        asm volatile("" :: "v"(s));   // keep replica computation live
    }
  }
}

// ---------------------------------------------------------------------------
extern "C" void kernel_launch(void* const* d_in, const int* in_sizes, int n_in,
                              void* d_out, int out_size, void* d_ws, size_t ws_size,
                              hipStream_t stream) {
  const int*   fids = (const int*)d_in[0];
  const int*   dom  = (const int*)d_in[1];
  const float* emb  = (const float*)d_in[2];
  const float* W1   = (const float*)d_in[3];
  const float* b1   = (const float*)d_in[4];
  const float* W2   = (const float*)d_in[5];
  const float* b2   = (const float*)d_in[6];
  const float* TW1  = (const float*)d_in[7];
  const float* Tb1  = (const float*)d_in[8];
  const float* TW2  = (const float*)d_in[9];
  const float* Tb2  = (const float*)d_in[10];
  const float* TW3  = (const float*)d_in[11];
  const float* Tb3  = (const float*)d_in[12];
  float* out = (float*)d_out;

  char* ws = (char*)d_ws;
  __bf16* W1P   = (__bf16*)(ws);
  __bf16* W2P   = (__bf16*)(ws + 655360);
  __bf16* TW1P  = (__bf16*)(ws + 917504);
  __bf16* TW2P  = (__bf16*)(ws + 1179648);

  k_prep<<<304, 256, 0, stream>>>(W1, W2, TW1, TW2, W1P, W2P, TW1P, TW2P);
  k_mega<<<256 * REP_MEGA, 512, 0, stream>>>(fids, dom, emb, W1P, b1, W2P, b2,
                                             TW1P, TW2P, Tb1, Tb2, TW3, Tb3,
                                             out);
}

// Round 16
// 46.429 us; speedup vs baseline: 5.7064x; 5.7064x over previous
//
#include <hip/hip_runtime.h>

#define B_SZ  16384
#define F_SZ  20
#define V_SZ  100000
#define E_SZ  32
#define DBOT  640
#define D1    512
#define D2    256
#define T1D   128
#define T2D   64
#define NDOM  4

typedef __bf16 bf16x8 __attribute__((ext_vector_type(8)));
typedef float  f32x4  __attribute__((ext_vector_type(4)));

#define MFMA(a, b, c) __builtin_amdgcn_mfma_f32_16x16x32_bf16((a), (b), (c), 0, 0, 0)

// ---------------------------------------------------------------------------
// Prep: pack weights into MFMA-fragment order bf16; block 304 packs TW3.
// ---------------------------------------------------------------------------
__global__ __launch_bounds__(256) void k_prep(const float* __restrict__ W1,
                                              const float* __restrict__ W2,
                                              const float* __restrict__ TW1,
                                              const float* __restrict__ TW2,
                                              const float* __restrict__ TW3,
                                              __bf16* __restrict__ W1P,
                                              __bf16* __restrict__ W2P,
                                              __bf16* __restrict__ TW1P,
                                              __bf16* __restrict__ TW2P,
                                              __bf16* __restrict__ TW3P) {
  int bid = blockIdx.x, tid = threadIdx.x;
  const float* src; __bf16* dst; int n, k, N;
  if (bid < 160) {
    long g = (long)bid * 256 + tid;
    int lane = g & 63; int kkg = (int)((g >> 6) % 20); int ntile = (int)(g / 1280);
    n = ntile * 16 + (lane & 15); k = kkg * 32 + ((lane >> 4) << 3);
    src = W1; N = D1; dst = W1P + g * 8;
  } else if (bid < 224) {
    long g = (long)(bid - 160) * 256 + tid;
    int lane = g & 63; int kkg = (int)((g >> 6) & 15); int ntile = (int)(g >> 10);
    n = ntile * 16 + (lane & 15); k = kkg * 32 + ((lane >> 4) << 3);
    src = W2; N = D2; dst = W2P + g * 8;
  } else if (bid < 288) {
    long g = (long)(bid - 224) * 256 + tid;
    int d = (int)(g >> 12); long r = g & 4095;
    int lane = r & 63; int kkg = (int)((r >> 6) & 7); int ntile = (int)(r >> 9);
    n = ntile * 16 + (lane & 15); k = kkg * 32 + ((lane >> 4) << 3);
    src = TW1 + (long)d * D2 * T1D; N = T1D;
    dst = TW1P + ((long)(d * 64 + ntile * 8 + kkg) * 64 + lane) * 8;
  } else if (bid < 304) {
    long g = (long)(bid - 288) * 256 + tid;
    int d = (int)(g >> 10); long r = g & 1023;
    int lane = r & 63; int kkg = (int)((r >> 6) & 3); int ntile = (int)(r >> 8);
    n = ntile * 16 + (lane & 15); k = kkg * 32 + ((lane >> 4) << 3);
    src = TW2 + (long)d * T1D * T2D; N = T2D;
    dst = TW2P + ((long)(d * 16 + ntile * 4 + kkg) * 64 + lane) * 8;
  } else {
    if (tid < NDOM * T2D) TW3P[tid] = (__bf16)TW3[tid];   // [d][k] flat
    return;
  }
  bf16x8 o;
#pragma unroll
  for (int e = 0; e < 8; ++e) o[e] = (__bf16)src[(long)(k + e) * N + n];
  *(bf16x8*)dst = o;
}

// ---------------------------------------------------------------------------
// MEGAFUSED (R14 base).  R16: (1) gather uses 3 rotating register sets with
// vmcnt-aware issue order (bfr(0) first, then g0-g2; per phase: commit |
// barrier | gather(g+3) | MFMA | bfr(next)) -> each gather rides 1.5-2.5
// phases in flight (was ~1), initial burst hides under kernel start.
// (2) final dot = MFMA with TW3 broadcast B-frag (replaces 32 conflicted
// scalar LDS reads + FMA chain + shfl per lane).
// ---------------------------------------------------------------------------
__global__ __launch_bounds__(512) void k_mega(const int* __restrict__ fids,
                                              const int* __restrict__ dom,
                                              const float* __restrict__ emb,
                                              const __bf16* __restrict__ W1P,
                                              const float* __restrict__ b1,
                                              const __bf16* __restrict__ W2P,
                                              const float* __restrict__ b2,
                                              const __bf16* __restrict__ TW1P,
                                              const __bf16* __restrict__ TW2P,
                                              const __bf16* __restrict__ TW3P,
                                              const float* __restrict__ Tb1,
                                              const float* __restrict__ Tb2,
                                              const float* __restrict__ Tb3,
                                              float* __restrict__ out) {
  __shared__ __attribute__((aligned(16))) char smem[152576];
  int*    ids_lds = (int*)(smem + 147456);        // 5120B (tail)
  __bf16* sA      = (__bf16*)smem;                // 81920B (rows 1280B, swz)
  __bf16* h1      = (__bf16*)(smem + 81920);      // 65536B (rows 1024B, swz)
  __bf16* h2_lds  = (__bf16*)smem;                // 32768B (rows 512B, swz)
  __bf16* t_lds   = (__bf16*)(smem + 81920);      // 64KB: 8 waves x 8KB

  int bid = blockIdx.x, tid = threadIdx.x;
  int lane = tid & 63, w = tid >> 6;
  int lrow = lane & 15, kq = lane >> 4;
  int m0 = bid * 64;

  // ---- stage feature ids ----
  for (int i = tid; i < 64 * F_SZ; i += 512) ids_lds[i] = fids[m0 * F_SZ + i];
  __syncthreads();

  // chunk mapping: c = tid (+512); row = c>>4, cc = c&15;
  // feature f = g*4 + (cc>>2), elems (cc&3)*8; sbyte(g) = base ^ swz + g*256.
  int row0 = tid >> 4,          cc0 = tid & 15;
  int row1 = (tid + 512) >> 4,  cc1 = tid & 15;
  int sb0 = (row0 * 1280 + cc0 * 16) ^ ((row0 & 7) << 4);
  int sb1 = (row1 * 1280 + cc1 * 16) ^ ((row1 & 7) << 4);
  int f0base = cc0 >> 2, es0 = (cc0 & 3) << 3;
  int f1base = cc1 >> 2, es1 = (cc1 & 3) << 3;

#define GATHER(G, P0, P1, P2, P3)                                            \
    { int f_ = (G) * 4 + f0base;                                             \
      int id_ = ids_lds[row0 * F_SZ + f_];                                   \
      const float* p_ = emb + ((long)f_ * V_SZ + id_) * E_SZ + es0;          \
      P0 = *(const float4*)p_; P1 = *(const float4*)(p_ + 4);                \
      f_ = (G) * 4 + f1base;                                                 \
      id_ = ids_lds[row1 * F_SZ + f_];                                       \
      const float* q_ = emb + ((long)f_ * V_SZ + id_) * E_SZ + es1;          \
      P2 = *(const float4*)q_; P3 = *(const float4*)(q_ + 4); }

#define COMMIT(S, P0, P1, P2, P3)                                            \
    { bf16x8 o_;                                                             \
      o_[0]=(__bf16)P0.x; o_[1]=(__bf16)P0.y; o_[2]=(__bf16)P0.z; o_[3]=(__bf16)P0.w; \
      o_[4]=(__bf16)P1.x; o_[5]=(__bf16)P1.y; o_[6]=(__bf16)P1.z; o_[7]=(__bf16)P1.w; \
      *(bf16x8*)((char*)sA + sb0 + (S) * 256) = o_;                          \
      o_[0]=(__bf16)P2.x; o_[1]=(__bf16)P2.y; o_[2]=(__bf16)P2.z; o_[3]=(__bf16)P2.w; \
      o_[4]=(__bf16)P3.x; o_[5]=(__bf16)P3.y; o_[6]=(__bf16)P3.z; o_[7]=(__bf16)P3.w; \
      *(bf16x8*)((char*)sA + sb1 + (S) * 256) = o_; }

#define BFRLOAD(G)                                                           \
    _Pragma("unroll")                                                        \
    for (int f4 = 0; f4 < 4; ++f4)                                           \
      _Pragma("unroll")                                                      \
      for (int ni = 0; ni < 4; ++ni)                                         \
        bfr[f4][ni] = *(const bf16x8*)(W1P +                                 \
            ((long)((w * 4 + ni) * 20 + (G) * 4 + f4) * 64 + lane) * 8);

#define SYNCP()                                                              \
    asm volatile("s_waitcnt lgkmcnt(0)" ::: "memory");                       \
    __builtin_amdgcn_s_barrier();                                            \
    __builtin_amdgcn_sched_barrier(0);

#define MFMAG(G)                                                             \
    _Pragma("unroll")                                                        \
    for (int f4 = 0; f4 < 4; ++f4) {                                         \
      int f_ = (G) * 4 + f4;                                                 \
      bf16x8 af[4];                                                          \
      _Pragma("unroll")                                                      \
      for (int mi = 0; mi < 4; ++mi) {                                       \
        int byte_ = ((mi * 16 + lrow) * 1280 + (f_ * 32 + kq * 8) * 2) ^ ((lrow & 7) << 4); \
        af[mi] = *(const bf16x8*)((const char*)sA + byte_);                  \
      }                                                                      \
      _Pragma("unroll")                                                      \
      for (int ni = 0; ni < 4; ++ni)                                         \
        _Pragma("unroll")                                                    \
        for (int mi = 0; mi < 4; ++mi)                                       \
          acc[mi][ni] = MFMA(af[mi], bfr[f4][ni], acc[mi][ni]);              \
    }

  float4 xA0, xA1, xB0, xB1, yA0, yA1, yB0, yB1, zA0, zA1, zB0, zB1;
  bf16x8 bfr[4][4];
  f32x4 acc[4][4] = {};

  // prologue: bfr(grp0) FIRST (oldest vmem -> its wait drains no gathers),
  // then 3-group gather burst.
  BFRLOAD(0)
  __builtin_amdgcn_sched_barrier(0);
  GATHER(0, xA0, xA1, xB0, xB1)
  GATHER(1, yA0, yA1, yB0, yB1)
  GATHER(2, zA0, zA1, zB0, zB1)

  // P0
  COMMIT(0, xA0, xA1, xB0, xB1)
  SYNCP()
  GATHER(3, xA0, xA1, xB0, xB1)
  __builtin_amdgcn_sched_barrier(0);
  MFMAG(0)
  BFRLOAD(1)
  // P1
  COMMIT(1, yA0, yA1, yB0, yB1)
  SYNCP()
  GATHER(4, yA0, yA1, yB0, yB1)
  __builtin_amdgcn_sched_barrier(0);
  MFMAG(1)
  BFRLOAD(2)
  // P2
  COMMIT(2, zA0, zA1, zB0, zB1)
  SYNCP()
  MFMAG(2)
  BFRLOAD(3)
  // P3
  COMMIT(3, xA0, xA1, xB0, xB1)
  SYNCP()
  MFMAG(3)
  BFRLOAD(4)
  // P4
  COMMIT(4, yA0, yA1, yB0, yB1)
  SYNCP()
  MFMAG(4)

#undef GATHER
#undef COMMIT
#undef BFRLOAD
#undef SYNCP
#undef MFMAG

  // ---- h1 = relu(. + b1) -> LDS (XOR-swizzled rows, 1024B stride) ----
#pragma unroll
  for (int ni = 0; ni < 4; ++ni) {
    int col = w * 64 + ni * 16 + lrow;
    float bv = b1[col];
#pragma unroll
    for (int mi = 0; mi < 4; ++mi) {
#pragma unroll
      for (int r = 0; r < 4; ++r) {
        int row = mi * 16 + kq * 4 + r;
        float v = acc[mi][ni][r] + bv;
        v = v > 0.f ? v : 0.f;
        int byte = (row * 1024 + col * 2) ^ ((row & 7) << 4);
        *(__bf16*)((char*)h1 + byte) = (__bf16)v;
      }
    }
  }
  __syncthreads();   // h1 complete; sA region dead -> h2_lds

  // ---- GEMM2 (barrier-free): h2[64x256] = relu(h1 @ W2 + b2) -> LDS ----
  {
    f32x4 acc2[4][2] = {};
#pragma unroll 4
    for (int kkg = 0; kkg < 16; ++kkg) {
      bf16x8 a2[4];
#pragma unroll
      for (int mi = 0; mi < 4; ++mi) {
        int byte = ((mi * 16 + lrow) * 1024 + kkg * 64 + kq * 16) ^ ((lrow & 7) << 4);
        a2[mi] = *(const bf16x8*)((const char*)h1 + byte);
      }
#pragma unroll
      for (int ni = 0; ni < 2; ++ni) {
        bf16x8 bfr2 = *(const bf16x8*)(W2P +
            ((long)((w * 2 + ni) * 16 + kkg) * 64 + lane) * 8);
#pragma unroll
        for (int mi = 0; mi < 4; ++mi)
          acc2[mi][ni] = MFMA(a2[mi], bfr2, acc2[mi][ni]);
      }
    }
#pragma unroll
    for (int ni = 0; ni < 2; ++ni) {
      int col = w * 32 + ni * 16 + lrow;
      float bv = b2[col];
#pragma unroll
      for (int mi = 0; mi < 4; ++mi) {
#pragma unroll
        for (int r = 0; r < 4; ++r) {
          int row = mi * 16 + kq * 4 + r;
          float v = acc2[mi][ni][r] + bv;
          v = v > 0.f ? v : 0.f;
          int byte = (row * 512 + col * 2) ^ ((row & 7) << 4);
          *(__bf16*)((char*)h2_lds + byte) = (__bf16)v;
        }
      }
    }
  }
  __syncthreads();   // h2 complete; h1 region dead -> t_lds

  // ---- Tower: wave w -> domain w>>1, rows (w&1)*32..+31, one pass ----
  {
    int d  = w >> 1;
    int r0 = (w & 1) * 32;
    __bf16* tw = t_lds + w * 4096;      // 8KB per wave (32 x 128 bf16)

    bf16x8 a1[2][8];
#pragma unroll
    for (int mi = 0; mi < 2; ++mi)
#pragma unroll
      for (int kk = 0; kk < 8; ++kk) {
        int row = r0 + mi * 16 + lrow;
        int byte = (row * 512 + (kk * 32 + kq * 8) * 2) ^ ((row & 7) << 4);
        a1[mi][kk] = *(const bf16x8*)((const char*)h2_lds + byte);
      }

    // t1 = relu(h2 @ TW1[d] + Tb1[d])  (32 x 128)
    f32x4 acc1[2][8] = {};
#pragma unroll
    for (int kk = 0; kk < 8; ++kk) {
#pragma unroll
      for (int ni = 0; ni < 8; ++ni) {
        bf16x8 b = *(const bf16x8*)(TW1P +
            ((long)(d * 64 + ni * 8 + kk) * 64 + lane) * 8);
#pragma unroll
        for (int mi = 0; mi < 2; ++mi)
          acc1[mi][ni] = MFMA(a1[mi][kk], b, acc1[mi][ni]);
      }
    }
#pragma unroll
    for (int ni = 0; ni < 8; ++ni) {
      float bv = Tb1[d * T1D + ni * 16 + lrow];
#pragma unroll
      for (int mi = 0; mi < 2; ++mi) {
#pragma unroll
        for (int r = 0; r < 4; ++r) {
          int lr = mi * 16 + kq * 4 + r;
          float v = acc1[mi][ni][r] + bv;
          v = v > 0.f ? v : 0.f;
          int byte = (lr * 256 + (ni * 16 + lrow) * 2) ^ ((lr & 7) << 4);
          *(__bf16*)((char*)tw + byte) = (__bf16)v;
        }
      }
    }
    asm volatile("s_waitcnt lgkmcnt(0)" ::: "memory");

    // t2 = relu(t1 @ TW2[d] + Tb2[d])  (32 x 64)
    bf16x8 a2f[2][4];
#pragma unroll
    for (int mi = 0; mi < 2; ++mi)
#pragma unroll
      for (int kk = 0; kk < 4; ++kk) {
        int lr = mi * 16 + lrow;
        int byte = (lr * 256 + (kk * 32 + kq * 8) * 2) ^ ((lr & 7) << 4);
        a2f[mi][kk] = *(const bf16x8*)((const char*)tw + byte);
      }
    asm volatile("s_waitcnt lgkmcnt(0)" ::: "memory");
    f32x4 acc2[2][4] = {};
#pragma unroll
    for (int kk = 0; kk < 4; ++kk) {
#pragma unroll
      for (int ni = 0; ni < 4; ++ni) {
        bf16x8 b = *(const bf16x8*)(TW2P +
            ((long)(d * 16 + ni * 4 + kk) * 64 + lane) * 8);
#pragma unroll
        for (int mi = 0; mi < 2; ++mi)
          acc2[mi][ni] = MFMA(a2f[mi][kk], b, acc2[mi][ni]);
      }
    }
#pragma unroll
    for (int ni = 0; ni < 4; ++ni) {
      float bv = Tb2[d * T2D + ni * 16 + lrow];
#pragma unroll
      for (int mi = 0; mi < 2; ++mi) {
#pragma unroll
        for (int r = 0; r < 4; ++r) {
          int lr = mi * 16 + kq * 4 + r;
          float v = acc2[mi][ni][r] + bv;
          v = v > 0.f ? v : 0.f;
          int byte = (lr * 128 + (ni * 16 + lrow) * 2) ^ ((lr & 7) << 4);
          *(__bf16*)((char*)tw + byte) = (__bf16)v;
        }
      }
    }
    asm volatile("s_waitcnt lgkmcnt(0)" ::: "memory");

    // ---- MFMA dot: logit[lr] = t2[lr][:] . TW3[d]  (B broadcast to all
    // cols -> every lane holds row-dots in C; lrow==0 lanes store) ----
    {
      bf16x8 b3_0 = *(const bf16x8*)(TW3P + d * 64 + kq * 8);
      bf16x8 b3_1 = *(const bf16x8*)(TW3P + d * 64 + 32 + kq * 8);
      f32x4 acc3[2] = {};
#pragma unroll
      for (int rt = 0; rt < 2; ++rt) {
        int lr = rt * 16 + lrow;
        int byte0 = (lr * 128 + (kq * 8) * 2) ^ ((lr & 7) << 4);
        int byte1 = (lr * 128 + (32 + kq * 8) * 2) ^ ((lr & 7) << 4);
        bf16x8 a3_0 = *(const bf16x8*)((const char*)tw + byte0);
        bf16x8 a3_1 = *(const bf16x8*)((const char*)tw + byte1);
        acc3[rt] = MFMA(a3_0, b3_0, acc3[rt]);
        acc3[rt] = MFMA(a3_1, b3_1, acc3[rt]);
      }
      if (lrow == 0) {
#pragma unroll
        for (int rt = 0; rt < 2; ++rt)
#pragma unroll
          for (int r = 0; r < 4; ++r) {
            int grow = r0 + rt * 16 + kq * 4 + r;
            if (dom[m0 + grow] == d) {
              float s = acc3[rt][r] + Tb3[d];
              out[m0 + grow] = 1.0f / (1.0f + expf(-s));
            }
          }
      }
    }
  }
}

// ---------------------------------------------------------------------------
extern "C" void kernel_launch(void* const* d_in, const int* in_sizes, int n_in,
                              void* d_out, int out_size, void* d_ws, size_t ws_size,
                              hipStream_t stream) {
  const int*   fids = (const int*)d_in[0];
  const int*   dom  = (const int*)d_in[1];
  const float* emb  = (const float*)d_in[2];
  const float* W1   = (const float*)d_in[3];
  const float* b1   = (const float*)d_in[4];
  const float* W2   = (const float*)d_in[5];
  const float* b2   = (const float*)d_in[6];
  const float* TW1  = (const float*)d_in[7];
  const float* Tb1  = (const float*)d_in[8];
  const float* TW2  = (const float*)d_in[9];
  const float* Tb2  = (const float*)d_in[10];
  const float* TW3  = (const float*)d_in[11];
  const float* Tb3  = (const float*)d_in[12];
  float* out = (float*)d_out;

  char* ws = (char*)d_ws;
  __bf16* W1P   = (__bf16*)(ws);                 // 655360
  __bf16* W2P   = (__bf16*)(ws + 655360);        // 262144
  __bf16* TW1P  = (__bf16*)(ws + 917504);        // 262144
  __bf16* TW2P  = (__bf16*)(ws + 1179648);       // 65536
  __bf16* TW3P  = (__bf16*)(ws + 1245184);       // 512

  k_prep<<<305, 256, 0, stream>>>(W1, W2, TW1, TW2, TW3,
                                  W1P, W2P, TW1P, TW2P, TW3P);
  k_mega<<<256, 512, 0, stream>>>(fids, dom, emb, W1P, b1, W2P, b2,
                                  TW1P, TW2P, TW3P, Tb1, Tb2, Tb3, out);
}

// Round 17
// 45.486 us; speedup vs baseline: 5.8246x; 1.0207x over previous
//
#include <hip/hip_runtime.h>

#define B_SZ  16384
#define F_SZ  20
#define V_SZ  100000
#define E_SZ  32
#define DBOT  640
#define D1    512
#define D2    256
#define T1D   128
#define T2D   64
#define NDOM  4

typedef __bf16 bf16x8 __attribute__((ext_vector_type(8)));
typedef float  f32x4  __attribute__((ext_vector_type(4)));

#define MFMA(a, b, c) __builtin_amdgcn_mfma_f32_16x16x32_bf16((a), (b), (c), 0, 0, 0)

// ---------------------------------------------------------------------------
// Prep: pack weights into MFMA-fragment order bf16; block 304 packs TW3.
// ---------------------------------------------------------------------------
__global__ __launch_bounds__(256) void k_prep(const float* __restrict__ W1,
                                              const float* __restrict__ W2,
                                              const float* __restrict__ TW1,
                                              const float* __restrict__ TW2,
                                              const float* __restrict__ TW3,
                                              __bf16* __restrict__ W1P,
                                              __bf16* __restrict__ W2P,
                                              __bf16* __restrict__ TW1P,
                                              __bf16* __restrict__ TW2P,
                                              __bf16* __restrict__ TW3P) {
  int bid = blockIdx.x, tid = threadIdx.x;
  const float* src; __bf16* dst; int n, k, N;
  if (bid < 160) {
    long g = (long)bid * 256 + tid;
    int lane = g & 63; int kkg = (int)((g >> 6) % 20); int ntile = (int)(g / 1280);
    n = ntile * 16 + (lane & 15); k = kkg * 32 + ((lane >> 4) << 3);
    src = W1; N = D1; dst = W1P + g * 8;
  } else if (bid < 224) {
    long g = (long)(bid - 160) * 256 + tid;
    int lane = g & 63; int kkg = (int)((g >> 6) & 15); int ntile = (int)(g >> 10);
    n = ntile * 16 + (lane & 15); k = kkg * 32 + ((lane >> 4) << 3);
    src = W2; N = D2; dst = W2P + g * 8;
  } else if (bid < 288) {
    long g = (long)(bid - 224) * 256 + tid;
    int d = (int)(g >> 12); long r = g & 4095;
    int lane = r & 63; int kkg = (int)((r >> 6) & 7); int ntile = (int)(r >> 9);
    n = ntile * 16 + (lane & 15); k = kkg * 32 + ((lane >> 4) << 3);
    src = TW1 + (long)d * D2 * T1D; N = T1D;
    dst = TW1P + ((long)(d * 64 + ntile * 8 + kkg) * 64 + lane) * 8;
  } else if (bid < 304) {
    long g = (long)(bid - 288) * 256 + tid;
    int d = (int)(g >> 10); long r = g & 1023;
    int lane = r & 63; int kkg = (int)((r >> 6) & 3); int ntile = (int)(r >> 8);
    n = ntile * 16 + (lane & 15); k = kkg * 32 + ((lane >> 4) << 3);
    src = TW2 + (long)d * T1D * T2D; N = T2D;
    dst = TW2P + ((long)(d * 16 + ntile * 4 + kkg) * 64 + lane) * 8;
  } else {
    if (tid < NDOM * T2D) TW3P[tid] = (__bf16)TW3[tid];   // [d][k] flat
    return;
  }
  bf16x8 o;
#pragma unroll
  for (int e = 0; e < 8; ++e) o[e] = (__bf16)src[(long)(k + e) * N + n];
  *(bf16x8*)dst = o;
}

// ---------------------------------------------------------------------------
// MEGAFUSED.  R17 = R14's gather/GEMM1 (1-ahead prefetch, 5 groups -- the
// 44.1us structure; R16's 3-deep rotation regressed +2.3us, reverted) +
// R16's MFMA-dot epilogue (TW3 broadcast B-frag replaces the 4-way-
// conflicted scalar dot; isolated at kernel tail, kept).
// ---------------------------------------------------------------------------
__global__ __launch_bounds__(512) void k_mega(const int* __restrict__ fids,
                                              const int* __restrict__ dom,
                                              const float* __restrict__ emb,
                                              const __bf16* __restrict__ W1P,
                                              const float* __restrict__ b1,
                                              const __bf16* __restrict__ W2P,
                                              const float* __restrict__ b2,
                                              const __bf16* __restrict__ TW1P,
                                              const __bf16* __restrict__ TW2P,
                                              const __bf16* __restrict__ TW3P,
                                              const float* __restrict__ Tb1,
                                              const float* __restrict__ Tb2,
                                              const float* __restrict__ Tb3,
                                              float* __restrict__ out) {
  __shared__ __attribute__((aligned(16))) char smem[152576];
  int*    ids_lds = (int*)(smem + 147456);        // 5120B (tail)
  __bf16* sA      = (__bf16*)smem;                // 81920B (rows 1280B, swz)
  __bf16* h1      = (__bf16*)(smem + 81920);      // 65536B (rows 1024B, swz)
  __bf16* h2_lds  = (__bf16*)smem;                // 32768B (rows 512B, swz)
  __bf16* t_lds   = (__bf16*)(smem + 81920);      // 64KB: 8 waves x 8KB

  int bid = blockIdx.x, tid = threadIdx.x;
  int lane = tid & 63, w = tid >> 6;
  int lrow = lane & 15, kq = lane >> 4;
  int m0 = bid * 64;

  // ---- stage feature ids ----
  for (int i = tid; i < 64 * F_SZ; i += 512) ids_lds[i] = fids[m0 * F_SZ + i];
  __syncthreads();

  // ---- pipelined gather + GEMM1 (R14 structure) ----
  int row0 = tid >> 4,          cc0 = tid & 15;
  int row1 = (tid + 512) >> 4,  cc1 = tid & 15;
  int sb0 = (row0 * 1280 + cc0 * 16) ^ ((row0 & 7) << 4);
  int sb1 = (row1 * 1280 + cc1 * 16) ^ ((row1 & 7) << 4);
  int f0base = cc0 >> 2, es0 = (cc0 & 3) << 3;
  int f1base = cc1 >> 2, es1 = (cc1 & 3) << 3;

  float4 g0a, g0b, g1a, g1b;
  {
    int f = f0base;
    int id = ids_lds[row0 * F_SZ + f];
    const float* p = emb + ((long)f * V_SZ + id) * E_SZ + es0;
    g0a = *(const float4*)p; g0b = *(const float4*)(p + 4);
    f = f1base;
    id = ids_lds[row1 * F_SZ + f];
    const float* q = emb + ((long)f * V_SZ + id) * E_SZ + es1;
    g1a = *(const float4*)q; g1b = *(const float4*)(q + 4);
  }

  f32x4 acc[4][4] = {};

#pragma unroll
  for (int g = 0; g < 5; ++g) {
    {
      bf16x8 o;
      o[0] = (__bf16)g0a.x; o[1] = (__bf16)g0a.y; o[2] = (__bf16)g0a.z; o[3] = (__bf16)g0a.w;
      o[4] = (__bf16)g0b.x; o[5] = (__bf16)g0b.y; o[6] = (__bf16)g0b.z; o[7] = (__bf16)g0b.w;
      *(bf16x8*)((char*)sA + sb0 + g * 256) = o;
      o[0] = (__bf16)g1a.x; o[1] = (__bf16)g1a.y; o[2] = (__bf16)g1a.z; o[3] = (__bf16)g1a.w;
      o[4] = (__bf16)g1b.x; o[5] = (__bf16)g1b.y; o[6] = (__bf16)g1b.z; o[7] = (__bf16)g1b.w;
      *(bf16x8*)((char*)sA + sb1 + g * 256) = o;
    }
    asm volatile("s_waitcnt lgkmcnt(0)" ::: "memory");
    __builtin_amdgcn_s_barrier();
    __builtin_amdgcn_sched_barrier(0);

    // prefetch B-frags for group g (issued BEFORE next gathers -> older)
    bf16x8 bfr[4][4];
#pragma unroll
    for (int f4 = 0; f4 < 4; ++f4)
#pragma unroll
      for (int ni = 0; ni < 4; ++ni)
        bfr[f4][ni] = *(const bf16x8*)(W1P +
            ((long)((w * 4 + ni) * 20 + g * 4 + f4) * 64 + lane) * 8);
    __builtin_amdgcn_sched_barrier(0);

    // issue gathers for group g+1 (YOUNGEST vmem)
    if (g < 4) {
      int f = (g + 1) * 4 + f0base;
      int id = ids_lds[row0 * F_SZ + f];
      const float* p = emb + ((long)f * V_SZ + id) * E_SZ + es0;
      g0a = *(const float4*)p; g0b = *(const float4*)(p + 4);
      f = (g + 1) * 4 + f1base;
      id = ids_lds[row1 * F_SZ + f];
      const float* q = emb + ((long)f * V_SZ + id) * E_SZ + es1;
      g1a = *(const float4*)q; g1b = *(const float4*)(q + 4);
    }
    __builtin_amdgcn_sched_barrier(0);

    // MFMA group g
#pragma unroll
    for (int f4 = 0; f4 < 4; ++f4) {
      int f = g * 4 + f4;
      bf16x8 af[4];
#pragma unroll
      for (int mi = 0; mi < 4; ++mi) {
        int byte = ((mi * 16 + lrow) * 1280 + (f * 32 + kq * 8) * 2) ^ ((lrow & 7) << 4);
        af[mi] = *(const bf16x8*)((const char*)sA + byte);
      }
#pragma unroll
      for (int ni = 0; ni < 4; ++ni)
#pragma unroll
        for (int mi = 0; mi < 4; ++mi)
          acc[mi][ni] = MFMA(af[mi], bfr[f4][ni], acc[mi][ni]);
    }
  }

  // ---- h1 = relu(. + b1) -> LDS (XOR-swizzled rows, 1024B stride) ----
#pragma unroll
  for (int ni = 0; ni < 4; ++ni) {
    int col = w * 64 + ni * 16 + lrow;
    float bv = b1[col];
#pragma unroll
    for (int mi = 0; mi < 4; ++mi) {
#pragma unroll
      for (int r = 0; r < 4; ++r) {
        int row = mi * 16 + kq * 4 + r;
        float v = acc[mi][ni][r] + bv;
        v = v > 0.f ? v : 0.f;
        int byte = (row * 1024 + col * 2) ^ ((row & 7) << 4);
        *(__bf16*)((char*)h1 + byte) = (__bf16)v;
      }
    }
  }
  __syncthreads();   // h1 complete; sA region dead -> h2_lds

  // ---- GEMM2 (barrier-free): h2[64x256] = relu(h1 @ W2 + b2) -> LDS ----
  {
    f32x4 acc2[4][2] = {};
#pragma unroll 4
    for (int kkg = 0; kkg < 16; ++kkg) {
      bf16x8 a2[4];
#pragma unroll
      for (int mi = 0; mi < 4; ++mi) {
        int byte = ((mi * 16 + lrow) * 1024 + kkg * 64 + kq * 16) ^ ((lrow & 7) << 4);
        a2[mi] = *(const bf16x8*)((const char*)h1 + byte);
      }
#pragma unroll
      for (int ni = 0; ni < 2; ++ni) {
        bf16x8 bfr2 = *(const bf16x8*)(W2P +
            ((long)((w * 2 + ni) * 16 + kkg) * 64 + lane) * 8);
#pragma unroll
        for (int mi = 0; mi < 4; ++mi)
          acc2[mi][ni] = MFMA(a2[mi], bfr2, acc2[mi][ni]);
      }
    }
#pragma unroll
    for (int ni = 0; ni < 2; ++ni) {
      int col = w * 32 + ni * 16 + lrow;
      float bv = b2[col];
#pragma unroll
      for (int mi = 0; mi < 4; ++mi) {
#pragma unroll
        for (int r = 0; r < 4; ++r) {
          int row = mi * 16 + kq * 4 + r;
          float v = acc2[mi][ni][r] + bv;
          v = v > 0.f ? v : 0.f;
          int byte = (row * 512 + col * 2) ^ ((row & 7) << 4);
          *(__bf16*)((char*)h2_lds + byte) = (__bf16)v;
        }
      }
    }
  }
  __syncthreads();   // h2 complete; h1 region dead -> t_lds

  // ---- Tower: wave w -> domain w>>1, rows (w&1)*32..+31, one pass ----
  {
    int d  = w >> 1;
    int r0 = (w & 1) * 32;
    __bf16* tw = t_lds + w * 4096;      // 8KB per wave (32 x 128 bf16)

    bf16x8 a1[2][8];
#pragma unroll
    for (int mi = 0; mi < 2; ++mi)
#pragma unroll
      for (int kk = 0; kk < 8; ++kk) {
        int row = r0 + mi * 16 + lrow;
        int byte = (row * 512 + (kk * 32 + kq * 8) * 2) ^ ((row & 7) << 4);
        a1[mi][kk] = *(const bf16x8*)((const char*)h2_lds + byte);
      }

    // t1 = relu(h2 @ TW1[d] + Tb1[d])  (32 x 128)
    f32x4 acc1[2][8] = {};
#pragma unroll
    for (int kk = 0; kk < 8; ++kk) {
#pragma unroll
      for (int ni = 0; ni < 8; ++ni) {
        bf16x8 b = *(const bf16x8*)(TW1P +
            ((long)(d * 64 + ni * 8 + kk) * 64 + lane) * 8);
#pragma unroll
        for (int mi = 0; mi < 2; ++mi)
          acc1[mi][ni] = MFMA(a1[mi][kk], b, acc1[mi][ni]);
      }
    }
#pragma unroll
    for (int ni = 0; ni < 8; ++ni) {
      float bv = Tb1[d * T1D + ni * 16 + lrow];
#pragma unroll
      for (int mi = 0; mi < 2; ++mi) {
#pragma unroll
        for (int r = 0; r < 4; ++r) {
          int lr = mi * 16 + kq * 4 + r;
          float v = acc1[mi][ni][r] + bv;
          v = v > 0.f ? v : 0.f;
          int byte = (lr * 256 + (ni * 16 + lrow) * 2) ^ ((lr & 7) << 4);
          *(__bf16*)((char*)tw + byte) = (__bf16)v;
        }
      }
    }
    asm volatile("s_waitcnt lgkmcnt(0)" ::: "memory");

    // t2 = relu(t1 @ TW2[d] + Tb2[d])  (32 x 64)
    bf16x8 a2f[2][4];
#pragma unroll
    for (int mi = 0; mi < 2; ++mi)
#pragma unroll
      for (int kk = 0; kk < 4; ++kk) {
        int lr = mi * 16 + lrow;
        int byte = (lr * 256 + (kk * 32 + kq * 8) * 2) ^ ((lr & 7) << 4);
        a2f[mi][kk] = *(const bf16x8*)((const char*)tw + byte);
      }
    asm volatile("s_waitcnt lgkmcnt(0)" ::: "memory");
    f32x4 acc2[2][4] = {};
#pragma unroll
    for (int kk = 0; kk < 4; ++kk) {
#pragma unroll
      for (int ni = 0; ni < 4; ++ni) {
        bf16x8 b = *(const bf16x8*)(TW2P +
            ((long)(d * 16 + ni * 4 + kk) * 64 + lane) * 8);
#pragma unroll
        for (int mi = 0; mi < 2; ++mi)
          acc2[mi][ni] = MFMA(a2f[mi][kk], b, acc2[mi][ni]);
      }
    }
#pragma unroll
    for (int ni = 0; ni < 4; ++ni) {
      float bv = Tb2[d * T2D + ni * 16 + lrow];
#pragma unroll
      for (int mi = 0; mi < 2; ++mi) {
#pragma unroll
        for (int r = 0; r < 4; ++r) {
          int lr = mi * 16 + kq * 4 + r;
          float v = acc2[mi][ni][r] + bv;
          v = v > 0.f ? v : 0.f;
          int byte = (lr * 128 + (ni * 16 + lrow) * 2) ^ ((lr & 7) << 4);
          *(__bf16*)((char*)tw + byte) = (__bf16)v;
        }
      }
    }
    asm volatile("s_waitcnt lgkmcnt(0)" ::: "memory");

    // ---- MFMA dot: logit[lr] = t2[lr][:] . TW3[d] (B broadcast -> every
    // lane's C row-dots; lrow==0 lanes store own-domain rows) ----
    {
      bf16x8 b3_0 = *(const bf16x8*)(TW3P + d * 64 + kq * 8);
      bf16x8 b3_1 = *(const bf16x8*)(TW3P + d * 64 + 32 + kq * 8);
      f32x4 acc3[2] = {};
#pragma unroll
      for (int rt = 0; rt < 2; ++rt) {
        int lr = rt * 16 + lrow;
        int byte0 = (lr * 128 + (kq * 8) * 2) ^ ((lr & 7) << 4);
        int byte1 = (lr * 128 + (32 + kq * 8) * 2) ^ ((lr & 7) << 4);
        bf16x8 a3_0 = *(const bf16x8*)((const char*)tw + byte0);
        bf16x8 a3_1 = *(const bf16x8*)((const char*)tw + byte1);
        acc3[rt] = MFMA(a3_0, b3_0, acc3[rt]);
        acc3[rt] = MFMA(a3_1, b3_1, acc3[rt]);
      }
      if (lrow == 0) {
#pragma unroll
        for (int rt = 0; rt < 2; ++rt)
#pragma unroll
          for (int r = 0; r < 4; ++r) {
            int grow = r0 + rt * 16 + kq * 4 + r;
            if (dom[m0 + grow] == d) {
              float s = acc3[rt][r] + Tb3[d];
              out[m0 + grow] = 1.0f / (1.0f + expf(-s));
            }
          }
      }
    }
  }
}

// ---------------------------------------------------------------------------
extern "C" void kernel_launch(void* const* d_in, const int* in_sizes, int n_in,
                              void* d_out, int out_size, void* d_ws, size_t ws_size,
                              hipStream_t stream) {
  const int*   fids = (const int*)d_in[0];
  const int*   dom  = (const int*)d_in[1];
  const float* emb  = (const float*)d_in[2];
  const float* W1   = (const float*)d_in[3];
  const float* b1   = (const float*)d_in[4];
  const float* W2   = (const float*)d_in[5];
  const float* b2   = (const float*)d_in[6];
  const float* TW1  = (const float*)d_in[7];
  const float* Tb1  = (const float*)d_in[8];
  const float* TW2  = (const float*)d_in[9];
  const float* Tb2  = (const float*)d_in[10];
  const float* TW3  = (const float*)d_in[11];
  const float* Tb3  = (const float*)d_in[12];
  float* out = (float*)d_out;

  char* ws = (char*)d_ws;
  __bf16* W1P   = (__bf16*)(ws);                 // 655360
  __bf16* W2P   = (__bf16*)(ws + 655360);        // 262144
  __bf16* TW1P  = (__bf16*)(ws + 917504);        // 262144
  __bf16* TW2P  = (__bf16*)(ws + 1179648);       // 65536
  __bf16* TW3P  = (__bf16*)(ws + 1245184);       // 512

  k_prep<<<305, 256, 0, stream>>>(W1, W2, TW1, TW2, TW3,
                                  W1P, W2P, TW1P, TW2P, TW3P);
  k_mega<<<256, 512, 0, stream>>>(fids, dom, emb, W1P, b1, W2P, b2,
                                  TW1P, TW2P, TW3P, Tb1, Tb2, Tb3, out);
}

// Round 18
// 43.916 us; speedup vs baseline: 6.0328x; 1.0357x over previous
//
#include <hip/hip_runtime.h>

#define B_SZ  16384
#define F_SZ  20
#define V_SZ  100000
#define E_SZ  32
#define DBOT  640
#define D1    512
#define D2    256
#define T1D   128
#define T2D   64
#define NDOM  4

typedef __bf16 bf16x8 __attribute__((ext_vector_type(8)));
typedef float  f32x4  __attribute__((ext_vector_type(4)));

#define MFMA(a, b, c) __builtin_amdgcn_mfma_f32_16x16x32_bf16((a), (b), (c), 0, 0, 0)

// ---------------------------------------------------------------------------
// Prep: pack all weights into MFMA-fragment order bf16.
// ---------------------------------------------------------------------------
__global__ __launch_bounds__(256) void k_prep(const float* __restrict__ W1,
                                              const float* __restrict__ W2,
                                              const float* __restrict__ TW1,
                                              const float* __restrict__ TW2,
                                              __bf16* __restrict__ W1P,
                                              __bf16* __restrict__ W2P,
                                              __bf16* __restrict__ TW1P,
                                              __bf16* __restrict__ TW2P) {
  int bid = blockIdx.x, tid = threadIdx.x;
  const float* src; __bf16* dst; int n, k, N;
  if (bid < 160) {
    long g = (long)bid * 256 + tid;
    int lane = g & 63; int kkg = (int)((g >> 6) % 20); int ntile = (int)(g / 1280);
    n = ntile * 16 + (lane & 15); k = kkg * 32 + ((lane >> 4) << 3);
    src = W1; N = D1; dst = W1P + g * 8;
  } else if (bid < 224) {
    long g = (long)(bid - 160) * 256 + tid;
    int lane = g & 63; int kkg = (int)((g >> 6) & 15); int ntile = (int)(g >> 10);
    n = ntile * 16 + (lane & 15); k = kkg * 32 + ((lane >> 4) << 3);
    src = W2; N = D2; dst = W2P + g * 8;
  } else if (bid < 288) {
    long g = (long)(bid - 224) * 256 + tid;
    int d = (int)(g >> 12); long r = g & 4095;
    int lane = r & 63; int kkg = (int)((r >> 6) & 7); int ntile = (int)(r >> 9);
    n = ntile * 16 + (lane & 15); k = kkg * 32 + ((lane >> 4) << 3);
    src = TW1 + (long)d * D2 * T1D; N = T1D;
    dst = TW1P + ((long)(d * 64 + ntile * 8 + kkg) * 64 + lane) * 8;
  } else {
    long g = (long)(bid - 288) * 256 + tid;
    int d = (int)(g >> 10); long r = g & 1023;
    int lane = r & 63; int kkg = (int)((r >> 6) & 3); int ntile = (int)(r >> 8);
    n = ntile * 16 + (lane & 15); k = kkg * 32 + ((lane >> 4) << 3);
    src = TW2 + (long)d * T1D * T2D; N = T2D;
    dst = TW2P + ((long)(d * 16 + ntile * 4 + kkg) * 64 + lane) * 8;
  }
  bf16x8 o;
#pragma unroll
  for (int e = 0; e < 8; ++e) o[e] = (__bf16)src[(long)(k + e) * N + n];
  *(bf16x8*)dst = o;
}

// ---------------------------------------------------------------------------
// MEGAFUSED (R14, session best = 44.1us): gather software-pipelined under
// GEMM1 (5 groups x 4 features, 1-ahead prefetch, lgkm-only barriers,
// youngest-gather vmem discipline) + GEMM2 in LDS + single-pass tower
// (wave w -> domain w>>1, rows (w&1)*32..+31) + scalar final dot.
// R16/R17 experiments (3-deep gather rotation, MFMA-dot epilogue) each
// regressed ~1us and are reverted.
// ---------------------------------------------------------------------------
__global__ __launch_bounds__(512) void k_mega(const int* __restrict__ fids,
                                              const int* __restrict__ dom,
                                              const float* __restrict__ emb,
                                              const __bf16* __restrict__ W1P,
                                              const float* __restrict__ b1,
                                              const __bf16* __restrict__ W2P,
                                              const float* __restrict__ b2,
                                              const __bf16* __restrict__ TW1P,
                                              const __bf16* __restrict__ TW2P,
                                              const float* __restrict__ Tb1,
                                              const float* __restrict__ Tb2,
                                              const float* __restrict__ TW3,
                                              const float* __restrict__ Tb3,
                                              float* __restrict__ out) {
  __shared__ __attribute__((aligned(16))) char smem[152576];
  int*    ids_lds = (int*)(smem + 147456);        // 5120B (tail)
  __bf16* sA      = (__bf16*)smem;                // 81920B (rows 1280B, swz)
  __bf16* h1      = (__bf16*)(smem + 81920);      // 65536B (rows 1024B, swz)
  __bf16* h2_lds  = (__bf16*)smem;                // 32768B (rows 512B, swz)
  __bf16* t_lds   = (__bf16*)(smem + 81920);      // 64KB: 8 waves x 8KB

  int bid = blockIdx.x, tid = threadIdx.x;
  int lane = tid & 63, w = tid >> 6;
  int lrow = lane & 15, kq = lane >> 4;
  int m0 = bid * 64;

  // ---- stage feature ids ----
  for (int i = tid; i < 64 * F_SZ; i += 512) ids_lds[i] = fids[m0 * F_SZ + i];
  __syncthreads();

  // ---- pipelined gather + GEMM1 ----
  // chunk mapping per group g: 1024 chunks c = tid + i*512 (i=0,1);
  // row = c>>4, cc16 = c&15; feature f = g*4 + (cc16>>2), elems (cc16&3)*8.
  // sbyte(g) = [(row*1280 + cc16*16) ^ ((row&7)<<4)] + g*256  (XOR commutes:
  // g*256 touches only bits >=8, swizzle XOR touches bits 4-6).
  int row0 = tid >> 4,          cc0 = tid & 15;
  int row1 = (tid + 512) >> 4,  cc1 = tid & 15;
  int sb0 = (row0 * 1280 + cc0 * 16) ^ ((row0 & 7) << 4);
  int sb1 = (row1 * 1280 + cc1 * 16) ^ ((row1 & 7) << 4);
  int f0base = cc0 >> 2, es0 = (cc0 & 3) << 3;
  int f1base = cc1 >> 2, es1 = (cc1 & 3) << 3;

  float4 g0a, g0b, g1a, g1b;
  // prologue: issue gathers for group 0
  {
    int f = f0base;
    int id = ids_lds[row0 * F_SZ + f];
    const float* p = emb + ((long)f * V_SZ + id) * E_SZ + es0;
    g0a = *(const float4*)p; g0b = *(const float4*)(p + 4);
    f = f1base;
    id = ids_lds[row1 * F_SZ + f];
    const float* q = emb + ((long)f * V_SZ + id) * E_SZ + es1;
    g1a = *(const float4*)q; g1b = *(const float4*)(q + 4);
  }

  f32x4 acc[4][4] = {};

#pragma unroll
  for (int g = 0; g < 5; ++g) {
    // commit group g staged regs -> sA (register dep waits the gathers)
    {
      bf16x8 o;
      o[0] = (__bf16)g0a.x; o[1] = (__bf16)g0a.y; o[2] = (__bf16)g0a.z; o[3] = (__bf16)g0a.w;
      o[4] = (__bf16)g0b.x; o[5] = (__bf16)g0b.y; o[6] = (__bf16)g0b.z; o[7] = (__bf16)g0b.w;
      *(bf16x8*)((char*)sA + sb0 + g * 256) = o;
      o[0] = (__bf16)g1a.x; o[1] = (__bf16)g1a.y; o[2] = (__bf16)g1a.z; o[3] = (__bf16)g1a.w;
      o[4] = (__bf16)g1b.x; o[5] = (__bf16)g1b.y; o[6] = (__bf16)g1b.z; o[7] = (__bf16)g1b.w;
      *(bf16x8*)((char*)sA + sb1 + g * 256) = o;
    }
    asm volatile("s_waitcnt lgkmcnt(0)" ::: "memory");
    __builtin_amdgcn_s_barrier();
    __builtin_amdgcn_sched_barrier(0);

    // prefetch B-frags for group g (issued BEFORE next gathers -> older)
    bf16x8 bfr[4][4];
#pragma unroll
    for (int f4 = 0; f4 < 4; ++f4)
#pragma unroll
      for (int ni = 0; ni < 4; ++ni)
        bfr[f4][ni] = *(const bf16x8*)(W1P +
            ((long)((w * 4 + ni) * 20 + g * 4 + f4) * 64 + lane) * 8);
    __builtin_amdgcn_sched_barrier(0);

    // issue gathers for group g+1 (YOUNGEST vmem)
    if (g < 4) {
      int f = (g + 1) * 4 + f0base;
      int id = ids_lds[row0 * F_SZ + f];
      const float* p = emb + ((long)f * V_SZ + id) * E_SZ + es0;
      g0a = *(const float4*)p; g0b = *(const float4*)(p + 4);
      f = (g + 1) * 4 + f1base;
      id = ids_lds[row1 * F_SZ + f];
      const float* q = emb + ((long)f * V_SZ + id) * E_SZ + es1;
      g1a = *(const float4*)q; g1b = *(const float4*)(q + 4);
    }
    __builtin_amdgcn_sched_barrier(0);

    // MFMA group g (af from sA, B from prefetched regs)
#pragma unroll
    for (int f4 = 0; f4 < 4; ++f4) {
      int f = g * 4 + f4;
      bf16x8 af[4];
#pragma unroll
      for (int mi = 0; mi < 4; ++mi) {
        int byte = ((mi * 16 + lrow) * 1280 + (f * 32 + kq * 8) * 2) ^ ((lrow & 7) << 4);
        af[mi] = *(const bf16x8*)((const char*)sA + byte);
      }
#pragma unroll
      for (int ni = 0; ni < 4; ++ni)
#pragma unroll
        for (int mi = 0; mi < 4; ++mi)
          acc[mi][ni] = MFMA(af[mi], bfr[f4][ni], acc[mi][ni]);
    }
  }

  // ---- h1 = relu(. + b1) -> LDS (XOR-swizzled rows, 1024B stride) ----
#pragma unroll
  for (int ni = 0; ni < 4; ++ni) {
    int col = w * 64 + ni * 16 + lrow;
    float bv = b1[col];
#pragma unroll
    for (int mi = 0; mi < 4; ++mi) {
#pragma unroll
      for (int r = 0; r < 4; ++r) {
        int row = mi * 16 + kq * 4 + r;
        float v = acc[mi][ni][r] + bv;
        v = v > 0.f ? v : 0.f;
        int byte = (row * 1024 + col * 2) ^ ((row & 7) << 4);
        *(__bf16*)((char*)h1 + byte) = (__bf16)v;
      }
    }
  }
  __syncthreads();   // h1 complete; sA region dead -> h2_lds

  // ---- GEMM2 (barrier-free): h2[64x256] = relu(h1 @ W2 + b2) -> LDS ----
  {
    f32x4 acc2[4][2] = {};
#pragma unroll 4
    for (int kkg = 0; kkg < 16; ++kkg) {
      bf16x8 a2[4];
#pragma unroll
      for (int mi = 0; mi < 4; ++mi) {
        int byte = ((mi * 16 + lrow) * 1024 + kkg * 64 + kq * 16) ^ ((lrow & 7) << 4);
        a2[mi] = *(const bf16x8*)((const char*)h1 + byte);
      }
#pragma unroll
      for (int ni = 0; ni < 2; ++ni) {
        bf16x8 bfr2 = *(const bf16x8*)(W2P +
            ((long)((w * 2 + ni) * 16 + kkg) * 64 + lane) * 8);
#pragma unroll
        for (int mi = 0; mi < 4; ++mi)
          acc2[mi][ni] = MFMA(a2[mi], bfr2, acc2[mi][ni]);
      }
    }
    // h2 -> LDS (rows 512B, swizzled by row&7)
#pragma unroll
    for (int ni = 0; ni < 2; ++ni) {
      int col = w * 32 + ni * 16 + lrow;
      float bv = b2[col];
#pragma unroll
      for (int mi = 0; mi < 4; ++mi) {
#pragma unroll
        for (int r = 0; r < 4; ++r) {
          int row = mi * 16 + kq * 4 + r;
          float v = acc2[mi][ni][r] + bv;
          v = v > 0.f ? v : 0.f;
          int byte = (row * 512 + col * 2) ^ ((row & 7) << 4);
          *(__bf16*)((char*)h2_lds + byte) = (__bf16)v;
        }
      }
    }
  }
  __syncthreads();   // h2 complete; h1 region dead -> t_lds

  // ---- Tower: wave w -> domain w>>1, rows (w&1)*32..+31, one pass ----
  {
    int d  = w >> 1;
    int r0 = (w & 1) * 32;
    __bf16* tw = t_lds + w * 4096;      // 8KB per wave (32 x 128 bf16)

    bf16x8 a1[2][8];
#pragma unroll
    for (int mi = 0; mi < 2; ++mi)
#pragma unroll
      for (int kk = 0; kk < 8; ++kk) {
        int row = r0 + mi * 16 + lrow;
        int byte = (row * 512 + (kk * 32 + kq * 8) * 2) ^ ((row & 7) << 4);
        a1[mi][kk] = *(const bf16x8*)((const char*)h2_lds + byte);
      }

    // t1 = relu(h2 @ TW1[d] + Tb1[d])  (32 x 128)
    f32x4 acc1[2][8] = {};
#pragma unroll
    for (int kk = 0; kk < 8; ++kk) {
#pragma unroll
      for (int ni = 0; ni < 8; ++ni) {
        bf16x8 b = *(const bf16x8*)(TW1P +
            ((long)(d * 64 + ni * 8 + kk) * 64 + lane) * 8);
#pragma unroll
        for (int mi = 0; mi < 2; ++mi)
          acc1[mi][ni] = MFMA(a1[mi][kk], b, acc1[mi][ni]);
      }
    }
#pragma unroll
    for (int ni = 0; ni < 8; ++ni) {
      float bv = Tb1[d * T1D + ni * 16 + lrow];
#pragma unroll
      for (int mi = 0; mi < 2; ++mi) {
#pragma unroll
        for (int r = 0; r < 4; ++r) {
          int lr = mi * 16 + kq * 4 + r;
          float v = acc1[mi][ni][r] + bv;
          v = v > 0.f ? v : 0.f;
          int byte = (lr * 256 + (ni * 16 + lrow) * 2) ^ ((lr & 7) << 4);
          *(__bf16*)((char*)tw + byte) = (__bf16)v;
        }
      }
    }
    asm volatile("s_waitcnt lgkmcnt(0)" ::: "memory");

    // t2 = relu(t1 @ TW2[d] + Tb2[d])  (32 x 64)
    bf16x8 a2f[2][4];
#pragma unroll
    for (int mi = 0; mi < 2; ++mi)
#pragma unroll
      for (int kk = 0; kk < 4; ++kk) {
        int lr = mi * 16 + lrow;
        int byte = (lr * 256 + (kk * 32 + kq * 8) * 2) ^ ((lr & 7) << 4);
        a2f[mi][kk] = *(const bf16x8*)((const char*)tw + byte);
      }
    asm volatile("s_waitcnt lgkmcnt(0)" ::: "memory");
    f32x4 acc2[2][4] = {};
#pragma unroll
    for (int kk = 0; kk < 4; ++kk) {
#pragma unroll
      for (int ni = 0; ni < 4; ++ni) {
        bf16x8 b = *(const bf16x8*)(TW2P +
            ((long)(d * 16 + ni * 4 + kk) * 64 + lane) * 8);
#pragma unroll
        for (int mi = 0; mi < 2; ++mi)
          acc2[mi][ni] = MFMA(a2f[mi][kk], b, acc2[mi][ni]);
      }
    }
#pragma unroll
    for (int ni = 0; ni < 4; ++ni) {
      float bv = Tb2[d * T2D + ni * 16 + lrow];
#pragma unroll
      for (int mi = 0; mi < 2; ++mi) {
#pragma unroll
        for (int r = 0; r < 4; ++r) {
          int lr = mi * 16 + kq * 4 + r;
          float v = acc2[mi][ni][r] + bv;
          v = v > 0.f ? v : 0.f;
          int byte = (lr * 128 + (ni * 16 + lrow) * 2) ^ ((lr & 7) << 4);
          *(__bf16*)((char*)tw + byte) = (__bf16)v;
        }
      }
    }
    asm volatile("s_waitcnt lgkmcnt(0)" ::: "memory");

    // logit + sigmoid + select-store.  lane -> local row lr = (kq&1)*16+lrow,
    // k-half = kq>>1 (32 elems each); lane^32 is the same row's other half.
    {
      int lr    = (kq & 1) * 16 + lrow;
      int khalf = kq >> 1;
      float s = 0.f;
#pragma unroll
      for (int j = 0; j < 32; ++j) {
        int col = khalf * 32 + j;
        int byte = (lr * 128 + col * 2) ^ ((lr & 7) << 4);
        s += (float)*(const __bf16*)((const char*)tw + byte) * TW3[d * T2D + col];
      }
      s += __shfl_xor(s, 32);
      s += Tb3[d];
      int grow = r0 + lr;
      if (khalf == 0 && dom[m0 + grow] == d)
        out[m0 + grow] = 1.0f / (1.0f + expf(-s));
    }
  }
}

// ---------------------------------------------------------------------------
extern "C" void kernel_launch(void* const* d_in, const int* in_sizes, int n_in,
                              void* d_out, int out_size, void* d_ws, size_t ws_size,
                              hipStream_t stream) {
  const int*   fids = (const int*)d_in[0];
  const int*   dom  = (const int*)d_in[1];
  const float* emb  = (const float*)d_in[2];
  const float* W1   = (const float*)d_in[3];
  const float* b1   = (const float*)d_in[4];
  const float* W2   = (const float*)d_in[5];
  const float* b2   = (const float*)d_in[6];
  const float* TW1  = (const float*)d_in[7];
  const float* Tb1  = (const float*)d_in[8];
  const float* TW2  = (const float*)d_in[9];
  const float* Tb2  = (const float*)d_in[10];
  const float* TW3  = (const float*)d_in[11];
  const float* Tb3  = (const float*)d_in[12];
  float* out = (float*)d_out;

  char* ws = (char*)d_ws;
  __bf16* W1P   = (__bf16*)(ws);                 // 655360
  __bf16* W2P   = (__bf16*)(ws + 655360);        // 262144
  __bf16* TW1P  = (__bf16*)(ws + 917504);        // 262144
  __bf16* TW2P  = (__bf16*)(ws + 1179648);       // 65536

  k_prep<<<304, 256, 0, stream>>>(W1, W2, TW1, TW2, W1P, W2P, TW1P, TW2P);
  k_mega<<<256, 512, 0, stream>>>(fids, dom, emb, W1P, b1, W2P, b2,
                                  TW1P, TW2P, Tb1, Tb2, TW3, Tb3, out);
}